// Round 1
// 431.170 us; speedup vs baseline: 1.0331x; 1.0331x over previous
//
#include <hip/hip_runtime.h>

#define POOL_SHIFT 2
#define GRID_DIM 64
#define NUM_CELLS 4096
#define NCH 64
#define BATCH 64
#define NSEG (BATCH * NUM_CELLS)   // 262,144 cells
#define SCAN_BLOCKS 1024           // NSEG / 256
#define RANK_BITS 14
#define RANK_MASK ((1u << RANK_BITS) - 1u)

// ---- K1: histogram + packed (cell,rank) per point ----
// cell < 2^18, rank < 2^14 (Poisson(3.8) per cell, max ~25) -> one u32.
__global__ __launch_bounds__(256) void count_kernel(
    const int* __restrict__ pos, const int* __restrict__ batch,
    unsigned int* __restrict__ counts, unsigned int* __restrict__ cellrank, int n) {
    int stride = gridDim.x * blockDim.x;
    for (int p = blockIdx.x * blockDim.x + threadIdx.x; p < n; p += stride) {
        long long t = __builtin_nontemporal_load((const long long*)pos + p);
        int px = (int)t;               // pos[p][0] (little-endian low word)
        int py = (int)(t >> 32);       // pos[p][1]
        int b  = __builtin_nontemporal_load(&batch[p]);
        int c  = b * NUM_CELLS + (px >> POOL_SHIFT) * GRID_DIM + (py >> POOL_SHIFT);
        unsigned int r = atomicAdd(&counts[c], 1u);
        __builtin_nontemporal_store(((unsigned int)c << RANK_BITS) | r, &cellrank[p]);
    }
}

// ---- K2a: per-256-chunk sums (wave shuffle reduce, 1 barrier) ----
__global__ __launch_bounds__(256) void reduce_kernel(
    const unsigned int* __restrict__ counts, unsigned int* __restrict__ blocksum) {
    __shared__ unsigned int ws[4];
    int t = threadIdx.x;
    unsigned int v = counts[blockIdx.x * 256 + t];
    #pragma unroll
    for (int off = 1; off < 64; off <<= 1) v += __shfl_xor((int)v, off, 64);
    if ((t & 63) == 0) ws[t >> 6] = v;
    __syncthreads();
    if (t == 0) blocksum[blockIdx.x] = ws[0] + ws[1] + ws[2] + ws[3];
}

// ---- K2b: exclusive scan of the 1024 chunk sums (single block, shfl scan) ----
__global__ __launch_bounds__(1024) void scanblock_kernel(
    const unsigned int* __restrict__ blocksum, unsigned int* __restrict__ blockbase) {
    __shared__ unsigned int wsum[16];
    int t = threadIdx.x, lane = t & 63, w = t >> 6;
    unsigned int own = blocksum[t];
    unsigned int v = own;
    #pragma unroll
    for (int off = 1; off < 64; off <<= 1) {
        unsigned int u = __shfl_up((int)v, off, 64);
        if (lane >= off) v += u;
    }
    if (lane == 63) wsum[w] = v;
    __syncthreads();
    unsigned int base = 0;
    for (int i = 0; i < w; ++i) base += wsum[i];
    blockbase[t] = v + base - own;   // exclusive
}

// ---- K2c: per-chunk exclusive scan + base -> global offsets ----
__global__ __launch_bounds__(256) void offsets_kernel(
    const unsigned int* __restrict__ counts, const unsigned int* __restrict__ blockbase,
    unsigned int* __restrict__ offsets, int n) {
    __shared__ unsigned int wsum[4];
    int t = threadIdx.x, b = blockIdx.x, lane = t & 63, w = t >> 6;
    unsigned int own = counts[b * 256 + t];
    unsigned int v = own;
    #pragma unroll
    for (int off = 1; off < 64; off <<= 1) {
        unsigned int u = __shfl_up((int)v, off, 64);
        if (lane >= off) v += u;
    }
    if (lane == 63) wsum[w] = v;
    __syncthreads();
    unsigned int base = blockbase[b];
    for (int i = 0; i < w; ++i) base += wsum[i];
    unsigned int incl = v + base;
    offsets[b * 256 + t] = incl - own;               // exclusive
    if (b == SCAN_BLOCKS - 1 && t == 255) offsets[NSEG] = incl;  // == n
}

// ---- K3: scatter point ids into cell-sorted order ----
__global__ __launch_bounds__(256) void reorder_kernel(
    const unsigned int* __restrict__ cellrank,
    const unsigned int* __restrict__ offsets, unsigned int* __restrict__ order, int n) {
    int stride = gridDim.x * blockDim.x;
    for (int p = blockIdx.x * blockDim.x + threadIdx.x; p < n; p += stride) {
        unsigned int u = __builtin_nontemporal_load(&cellrank[p]);
        unsigned int c = u >> RANK_BITS;
        order[offsets[c] + (u & RANK_MASK)] = (unsigned int)p;
    }
}

// ---- K4: grid-stride, one wave per cell per iteration, lane = channel ----
// 2048 blocks = 8192 waves = exactly full residency; 32 cells/wave, no
// workgroup redispatch. x/out are touch-once -> nontemporal; order/offsets
// have cross-wave line reuse -> cached.
__global__ __launch_bounds__(256) void gather_kernel(
    const float* __restrict__ x, const unsigned int* __restrict__ offsets,
    const unsigned int* __restrict__ order, float* __restrict__ out) {
    int lane = threadIdx.x & 63;
    int gw = (int)((blockIdx.x * blockDim.x + threadIdx.x) >> 6);
    int nw = (int)((gridDim.x * blockDim.x) >> 6);
    const float NEG_INF = -__builtin_inff();

    for (int cell = gw; cell < NSEG; cell += nw) {
        unsigned int s = offsets[cell];
        unsigned int e = offsets[cell + 1];
        size_t obase = (size_t)cell * NCH + lane;
        if (s == e) { __builtin_nontemporal_store(0.0f, &out[obase]); continue; }

        float acc = NEG_INF;
        for (unsigned int base = s; base < e; base += 64) {
            unsigned int rem = e - base;                 // wave-uniform
            unsigned int cnt = rem < 64u ? rem : 64u;
            unsigned int li = (unsigned int)lane < cnt ? (unsigned int)lane : cnt - 1u;
            unsigned int myp = order[base + li];

            for (unsigned int j = 0; j < cnt; j += 4) {  // uniform trip count
                unsigned int m = cnt - j;
                unsigned int p0 = (unsigned int)__shfl((int)myp, (int)j, 64);
                float v0 = __builtin_nontemporal_load(&x[(size_t)p0 * NCH + lane]);
                float v1 = NEG_INF, v2 = NEG_INF, v3 = NEG_INF;
                if (m > 1u) {
                    unsigned int p1 = (unsigned int)__shfl((int)myp, (int)(j + 1), 64);
                    v1 = __builtin_nontemporal_load(&x[(size_t)p1 * NCH + lane]);
                }
                if (m > 2u) {
                    unsigned int p2 = (unsigned int)__shfl((int)myp, (int)(j + 2), 64);
                    v2 = __builtin_nontemporal_load(&x[(size_t)p2 * NCH + lane]);
                }
                if (m > 3u) {
                    unsigned int p3 = (unsigned int)__shfl((int)myp, (int)(j + 3), 64);
                    v3 = __builtin_nontemporal_load(&x[(size_t)p3 * NCH + lane]);
                }
                acc = fmaxf(acc, fmaxf(fmaxf(v0, v1), fmaxf(v2, v3)));
            }
        }
        __builtin_nontemporal_store(acc, &out[obase]);
    }
}

extern "C" void kernel_launch(void* const* d_in, const int* in_sizes, int n_in,
                              void* d_out, int out_size, void* d_ws, size_t ws_size,
                              hipStream_t stream) {
    const float* x   = (const float*)d_in[0];
    const int* pos   = (const int*)d_in[1];
    const int* batch = (const int*)d_in[2];
    float* out = (float*)d_out;
    int n = in_sizes[2];

    // workspace layout (~10 MB)
    unsigned int* counts    = (unsigned int*)d_ws;          // NSEG
    unsigned int* offsets   = counts + NSEG;                // NSEG + 1
    unsigned int* blocksum  = offsets + NSEG + 1;           // 1024
    unsigned int* blockbase = blocksum + 1024;              // 1024
    unsigned int* cellrank  = blockbase + 1024;             // N
    unsigned int* order     = cellrank + n;                 // N

    hipMemsetAsync(counts, 0, (size_t)NSEG * sizeof(unsigned int), stream);

    count_kernel<<<4096, 256, 0, stream>>>(pos, batch, counts, cellrank, n);
    reduce_kernel<<<SCAN_BLOCKS, 256, 0, stream>>>(counts, blocksum);
    scanblock_kernel<<<1, 1024, 0, stream>>>(blocksum, blockbase);
    offsets_kernel<<<SCAN_BLOCKS, 256, 0, stream>>>(counts, blockbase, offsets, n);
    reorder_kernel<<<4096, 256, 0, stream>>>(cellrank, offsets, order, n);
    gather_kernel<<<2048, 256, 0, stream>>>(x, offsets, order, out);
}